// Round 9
// baseline (792.178 us; speedup 1.0000x reference)
//
#include <hip/hip_runtime.h>
#include <hip/hip_bf16.h>
#include <cstdint>
#include <cmath>

#define AS1 __attribute__((address_space(1)))
#define AS3 __attribute__((address_space(3)))

typedef unsigned short u16;
typedef uint32_t u32;
typedef __attribute__((ext_vector_type(8))) __bf16 bf16x8;
typedef __attribute__((ext_vector_type(8))) unsigned short u16x8;
typedef __attribute__((ext_vector_type(4))) float f32x4;

// R23: leaf -> 2-slot / 80 KB LDS / 2 blocks-per-CU (fill the ~1100 cyc/tile
// stall with TLP); gemm_hwc h-role -> 2-slot K32 rolling pipeline INSIDE the
// verified R19 grid/layout (only the loop schedule changes). wc role, setup,
// finalize byte-identical to R22 (passed, 198.5 us).

// fp32 -> bf16 round-to-nearest-even
__device__ __forceinline__ u16 f2bf(float f) {
    uint32_t u = __builtin_bit_cast(uint32_t, f);
    return (u16)((u + 0x7fffu + ((u >> 16) & 1u)) >> 16);
}

// order-preserving float -> u32 map (for integer atomicMax); 0 is below all reals
__device__ __forceinline__ u32 f2ord(float f) {
    u32 u = __builtin_bit_cast(u32, f);
    return u ^ (u32)(((int32_t)u >> 31) | 0x80000000);
}
__device__ __forceinline__ float ord2f(u32 v) {
    u32 u = (v & 0x80000000u) ? (v ^ 0x80000000u) : ~v;
    return __builtin_bit_cast(float, u);
}

// SWIZZLE (R16-proven, both-sides involution, rule #21): LDS panels [rows][32 u16]
// (64 B row stride). LDS[row][chunk c] holds GLOBAL chunk c ^ ((row>>1)&3), staged
// via pre-swizzled global source (LDS dest stays linear for global_load_lds);
// read chunk = q ^ ((i16>>1)&3) -> registers hold the STANDARD fragment.
//   stage key: (tid>>3)&3   read key: (i16>>1)&3

// ---------------- fused setup (= R19) ----------------
// ALGEBRA: relu(h)=(h+|h|)/2, relu(-h)=(|h|-h)/2  =>
//   leaf = |h| @ Ws^T + x @ Wc^T + cl
__global__ void setup_all(const float* __restrict__ x,
                          const float* __restrict__ Wd, const float* __restrict__ bd,
                          const float* __restrict__ Wa, const float* __restrict__ ba,
                          const float* __restrict__ Wl,
                          u16* __restrict__ xb, u16* __restrict__ w1b,
                          float* __restrict__ bb, u16* __restrict__ w1t,
                          u16* __restrict__ wsb, u16* __restrict__ dlb,
                          float* __restrict__ cl, u32* __restrict__ pooled) {
    __shared__ float cred[256];
    const int b = blockIdx.x;
    const int tid = threadIdx.x;
    if (b < 2048) {
        long idx = (long)(b * 256 + tid) * 8;
        float4 a = *(const float4*)(x + idx);
        float4 c = *(const float4*)(x + idx + 4);
        u16x8 o;
        o[0]=f2bf(a.x); o[1]=f2bf(a.y); o[2]=f2bf(a.z); o[3]=f2bf(a.w);
        o[4]=f2bf(c.x); o[5]=f2bf(c.y); o[6]=f2bf(c.z); o[7]=f2bf(c.w);
        *(u16x8*)(xb + idx) = o;
    } else if (b < 2112) {
        int t = (b - 2048) * 256 + tid;   // 16384 threads
        int row = t >> 4, g = (t & 15) * 8;
        const float* src = nullptr;
        if (row < 511)       src = Wd + row * 128 + g;
        else if (row < 1023) src = Wa + (row - 511) * 128 + g;
        u16x8 o = 0;
        if (src) {
            #pragma unroll
            for (int j = 0; j < 8; ++j) o[j] = f2bf(src[j]);
        }
        *(u16x8*)(w1b + row * 128 + g) = o;
        #pragma unroll
        for (int j = 0; j < 8; ++j) w1t[(g + j) * 1024 + row] = o[j];
        if ((t & 15) == 0)
            bb[row] = row < 511 ? bd[row] : (row < 1023 ? ba[row - 511] : 0.f);
    } else if (b < 2624) {
        const int l0 = (b - 2112) * 2;
        const int lo = tid >> 7, g = (tid & 127) * 8;
        const float* src = Wl + (long)(l0 + lo) * 2046;
        u16x8 os, od;
        float part = 0.f;
        #pragma unroll
        for (int j = 0; j < 8; ++j) {
            int c = g + j;
            float pa = 0.f, pb = 0.f;
            if (c < 1023) { pa = src[c]; pb = src[1023 + c]; }
            os[j] = f2bf(0.5f * (pa + pb));
            float v = pa - pb;
            od[j] = f2bf(v);
            float b1 = c < 511 ? bd[c] : (c < 1023 ? ba[c - 511] : 0.f);
            part += v * b1;
        }
        *(u16x8*)(wsb + (long)(l0 + lo) * 1024 + g) = os;
        *(u16x8*)(dlb + (long)(l0 + lo) * 1024 + g) = od;
        cred[tid] = part;
        __syncthreads();
        if (tid < 2) {
            float s = 0.f;
            #pragma unroll
            for (int k = 0; k < 128; ++k) s += cred[tid * 128 + k];
            cl[l0 + tid] = 0.5f * s;
        }
    } else {
        // zero pooled[32768][16] u32 (2 MB) — every iteration
        uint4* p4 = (uint4*)pooled;            // 131072 uint4
        const int base = (b - 2624) * 16384;   // 8 blocks x 16384 uint4
        #pragma unroll
        for (int j = 0; j < 64; ++j)
            p4[base + tid + j * 256] = uint4{0u, 0u, 0u, 0u};
    }
}

// ---------------- gemm_hwc: R19 grid/layout; h-role loop -> 2-slot K32 rolling ----
__global__ __launch_bounds__(256) void gemm_hwc(
        const u16* __restrict__ xb, const u16* __restrict__ w1b,
        const float* __restrict__ bb,
        const u16* __restrict__ dlb, const u16* __restrict__ w1t,
        u16* __restrict__ habs, u16* __restrict__ wcb) {
    __shared__ union SharedU {
        struct { u16 As[2][4096]; u16 Bs[2][4096]; } s;  // 32 KB, 2 K32-slots
        u16 obuf[128 * 132];                             // 33.8 KB epilogue overlay
    } sh;
    const int tid  = threadIdx.x;
    const int lane = tid & 63, wave = tid >> 6;
    const int wy = wave >> 1, wx = wave & 1;
    const int i16 = lane & 15, q = lane >> 4;
    const int cA = wave * 2, srow = lane >> 2;
    const int scol = (((lane & 3) ^ ((lane >> 3) & 3))) * 8;  // source-swizzled chunk
    const int qa   = (q ^ ((i16 >> 1) & 3)) * 8;              // swizzled read chunk

    f32x4 acc[4][4];
    #pragma unroll
    for (int m = 0; m < 4; ++m)
        #pragma unroll
        for (int n = 0; n < 4; ++n) acc[m][n] = f32x4{0.f,0.f,0.f,0.f};

    if (blockIdx.y == 0) {
        // ---- wc role (= R19 verbatim): Wc = 0.5*dlb@w1t^T, K=1024, BK=32 ----
        const long blockM = (long)blockIdx.x * 128;
        const int koff = (blockIdx.x * 4) & 31;
        const u16* a0 = dlb + (blockM + cA * 16 + srow) * 1024 + scol;
        const u16* a1 = dlb + (blockM + (cA + 1) * 16 + srow) * 1024 + scol;
        const u16* b0 = w1t + (long)(cA * 16 + srow) * 1024 + scol;
        const u16* b1 = w1t + (long)((cA + 1) * 16 + srow) * 1024 + scol;
        for (int it = 0; it < 32; ++it) {
            const int k0 = ((it + koff) & 31) << 5;
            __builtin_amdgcn_global_load_lds((const AS1 void*)(a0 + k0), (AS3 void*)&sh.s.As[0][cA * 512],       16, 0, 0);
            __builtin_amdgcn_global_load_lds((const AS1 void*)(a1 + k0), (AS3 void*)&sh.s.As[0][(cA + 1) * 512], 16, 0, 0);
            __builtin_amdgcn_global_load_lds((const AS1 void*)(b0 + k0), (AS3 void*)&sh.s.Bs[0][cA * 512],       16, 0, 0);
            __builtin_amdgcn_global_load_lds((const AS1 void*)(b1 + k0), (AS3 void*)&sh.s.Bs[0][(cA + 1) * 512], 16, 0, 0);
            __syncthreads();
            bf16x8 af[4], bfv[4];
            #pragma unroll
            for (int s = 0; s < 4; ++s) {
                af[s]  = *(const bf16x8*)&sh.s.As[0][(wy * 64 + s * 16 + i16) * 32 + qa];
                bfv[s] = *(const bf16x8*)&sh.s.Bs[0][(wx * 64 + s * 16 + i16) * 32 + qa];
            }
            #pragma unroll
            for (int sm = 0; sm < 4; ++sm)
                #pragma unroll
                for (int sn = 0; sn < 4; ++sn)
                    acc[sm][sn] = __builtin_amdgcn_mfma_f32_16x16x32_bf16(af[sm], bfv[sn], acc[sm][sn], 0, 0, 0);
            __syncthreads();
        }
        #pragma unroll
        for (int sm = 0; sm < 4; ++sm)
            #pragma unroll
            for (int sn = 0; sn < 4; ++sn) {
                const int col = wx * 64 + sn * 16 + i16;     // 0..127
                #pragma unroll
                for (int r = 0; r < 4; ++r) {
                    const long row = blockM + wy * 64 + sm * 16 + 4 * q + r;
                    wcb[row * 128 + col] = f2bf(0.5f * acc[sm][sn][r]);
                }
            }
        return;
    }

    // ---- h role: habs = |xb @ w1b^T + bb|, K=128 = 4 K32-tiles, 2-slot rolling ----
    const int xcd = blockIdx.x, yy = blockIdx.y - 1;   // yy in 0..255
    const long blockM = (long)(xcd * 32 + (yy >> 3)) * 128;
    const int  blockN = (yy & 7) * 128;

    const u16* a0 = xb + (blockM + cA * 16 + srow) * 128 + scol;
    const u16* a1 = xb + (blockM + (cA + 1) * 16 + srow) * 128 + scol;
    const u16* b0 = w1b + ((long)blockN + cA * 16 + srow) * 128 + scol;
    const u16* b1 = w1b + ((long)blockN + (cA + 1) * 16 + srow) * 128 + scol;
    auto hstage = [&](int tt) {            // one K32 tile = 4 ops/thread
        const int sl = tt & 1, kp = tt * 32;
        __builtin_amdgcn_global_load_lds((const AS1 void*)(a0 + kp), (AS3 void*)&sh.s.As[sl][cA * 512],       16, 0, 0);
        __builtin_amdgcn_global_load_lds((const AS1 void*)(a1 + kp), (AS3 void*)&sh.s.As[sl][(cA + 1) * 512], 16, 0, 0);
        __builtin_amdgcn_global_load_lds((const AS1 void*)(b0 + kp), (AS3 void*)&sh.s.Bs[sl][cA * 512],       16, 0, 0);
        __builtin_amdgcn_global_load_lds((const AS1 void*)(b1 + kp), (AS3 void*)&sh.s.Bs[sl][(cA + 1) * 512], 16, 0, 0);
    };
    hstage(0);
    asm volatile("s_waitcnt vmcnt(0)" ::: "memory");
    __builtin_amdgcn_s_barrier();
    #pragma unroll
    for (int kt = 0; kt < 4; ++kt) {
        const int sl = kt & 1;
        __builtin_amdgcn_sched_barrier(0);
        bf16x8 af[4], bfv[4];
        #pragma unroll
        for (int s = 0; s < 4; ++s) {
            af[s]  = *(const bf16x8*)&sh.s.As[sl][(wy * 64 + s * 16 + i16) * 32 + qa];
            bfv[s] = *(const bf16x8*)&sh.s.Bs[sl][(wx * 64 + s * 16 + i16) * 32 + qa];
        }
        if (kt + 1 < 4) hstage(kt + 1);    // other slot; WAR: last read at kt-1, drained
        asm volatile("s_waitcnt lgkmcnt(0)" ::: "memory");
        __builtin_amdgcn_sched_barrier(0);
        __builtin_amdgcn_s_setprio(1);
        #pragma unroll
        for (int sm = 0; sm < 4; ++sm)
            #pragma unroll
            for (int sn = 0; sn < 4; ++sn)
                acc[sm][sn] = __builtin_amdgcn_mfma_f32_16x16x32_bf16(af[sm], bfv[sn], acc[sm][sn], 0, 0, 0);
        __builtin_amdgcn_s_setprio(0);
        if (kt + 1 < 4) { asm volatile("s_waitcnt vmcnt(0)" ::: "memory"); }
        __builtin_amdgcn_s_barrier();      // tile kt+1 resident; also final pre-obuf sync
    }

    float bv[4];
    #pragma unroll
    for (int sn = 0; sn < 4; ++sn) bv[sn] = bb[blockN + wx * 64 + sn * 16 + i16];
    #pragma unroll
    for (int sm = 0; sm < 4; ++sm)
        #pragma unroll
        for (int sn = 0; sn < 4; ++sn)
            #pragma unroll
            for (int r = 0; r < 4; ++r)
                sh.obuf[(wy * 64 + sm * 16 + 4 * q + r) * 132 + wx * 64 + sn * 16 + i16] =
                    f2bf(fabsf(acc[sm][sn][r] + bv[sn]));
    __syncthreads();
    const int cg = (tid & 15) * 8;
    #pragma unroll
    for (int it = 0; it < 8; ++it) {
        const int row = it * 16 + (tid >> 4);
        *(u16x8*)&habs[(blockM + row) * 1024 + blockN + cg] =
            *(const u16x8*)&sh.obuf[row * 132 + cg];
    }
}

// ---------------- GEMM2 (R23): 2-slot, 80 KB LDS -> 2 blocks/CU ----------------
// leaf = habs@Ws^T + xb@Wc^T + cl, fused ragged-max -> global atomicMax(pooled).
// K-tiles t=0..31: habs/wsb (stride 1024); t=32..35: xb/wcb (stride 128).
// Slot = t&1. stage(t+1) during tile t (other slot; WAR: its reads drained at
// t-1's lgkm(0), before the barrier preceding this stage). vmcnt(0) gate at
// tile end (stage latency ~900cyc hidden under ~2900cyc tile). Early-reads of
// tile t+1 (8 mh0+breg ds_reads) after the barrier, as in R22.
__global__ __launch_bounds__(512, 4) void gemm_leaf(const u16* __restrict__ habs,
        const u16* __restrict__ xb, const u16* __restrict__ wsb,
        const u16* __restrict__ wcb, const float* __restrict__ cl,
        const int* __restrict__ seg, u32* __restrict__ pooled) {
    __shared__ __align__(16) u16 As[2][256 * 32];   // 32 KB, 2 K32-slots
    __shared__ __align__(16) u16 Bs[2][256 * 32];   // 32 KB
    __shared__ u32 pmax[256 * 16];                  // 16 KB  => 80 KB, 2 blocks/CU
    const int tid  = threadIdx.x;
    const int lane = tid & 63, w = tid >> 6;
    const int wm = w >> 2, wn = w & 3;              // 2x4 wave grid, wave tile 128x64
    const int i16 = lane & 15, q = lane >> 4;

    // XCD-aware swizzle over 512 blocks (512%8==0 -> bijective)
    const int bid  = blockIdx.x;
    const int wgid = (bid & 7) * 64 + (bid >> 3);
    const int mT = wgid >> 2, nT = wgid & 3;
    const long blockM = (long)mT * 256;
    const int  blockN = nT * 256;

    #pragma unroll
    for (int j = 0; j < 8; ++j) pmax[tid + j * 512] = 0u;   // below all reals

    const int r0 = tid >> 2;
    const int scol = (((tid & 3) ^ ((tid >> 3) & 3))) * 8;
    const u16* gA1 = habs + (blockM + r0) * 1024 + scol;
    const u16* gB1 = wsb  + (long)(blockN + r0) * 1024 + scol;
    const u16* gA2 = xb   + (blockM + r0) * 128 + scol;
    const u16* gB2 = wcb  + (long)(blockN + r0) * 128 + scol;
    const int ldsb = w * 512;                       // wave-uniform dest base (u16)

    auto stageA = [&](int tt) {
        u16* dst = &As[tt & 1][ldsb];
        const u16* g; int jstr;
        if (tt < 32) { g = gA1 + tt * 32;        jstr = 128 * 1024; }
        else         { g = gA2 + (tt - 32) * 32; jstr = 128 * 128; }
        __builtin_amdgcn_global_load_lds((const AS1 void*)g,          (AS3 void*)dst,          16, 0, 0);
        __builtin_amdgcn_global_load_lds((const AS1 void*)(g + jstr), (AS3 void*)(dst + 4096), 16, 0, 0);
    };
    auto stageB = [&](int tt) {
        u16* dst = &Bs[tt & 1][ldsb];
        const u16* g; int jstr;
        if (tt < 32) { g = gB1 + tt * 32;        jstr = 128 * 1024; }
        else         { g = gB2 + (tt - 32) * 32; jstr = 128 * 128; }
        __builtin_amdgcn_global_load_lds((const AS1 void*)g,          (AS3 void*)dst,          16, 0, 0);
        __builtin_amdgcn_global_load_lds((const AS1 void*)(g + jstr), (AS3 void*)(dst + 4096), 16, 0, 0);
    };

    f32x4 acc[8][4];
    #pragma unroll
    for (int m = 0; m < 8; ++m)
        #pragma unroll
        for (int n = 0; n < 4; ++n) acc[m][n] = f32x4{0.f,0.f,0.f,0.f};
    bf16x8 a0r[4], a1r[4], br[4];

    const int rdc = (q ^ ((i16 >> 1) & 3)) * 8;     // swizzled read chunk (u16 off)
    auto lda = [&](bf16x8* ar, int slot, int mh) {
        #pragma unroll
        for (int mf = 0; mf < 4; ++mf)
            ar[mf] = *(const bf16x8*)&As[slot][(wm * 128 + mh * 64 + mf * 16 + i16) * 32 + rdc];
    };
    auto ldb = [&](int slot) {
        #pragma unroll
        for (int nf = 0; nf < 4; ++nf)
            br[nf] = *(const bf16x8*)&Bs[slot][(wn * 64 + nf * 16 + i16) * 32 + rdc];
    };
    auto mf16 = [&](const bf16x8* ar, int mh) {
        #pragma unroll
        for (int mf = 0; mf < 4; ++mf)
            #pragma unroll
            for (int nf = 0; nf < 4; ++nf)
                acc[mh * 4 + mf][nf] = __builtin_amdgcn_mfma_f32_16x16x32_bf16(
                    ar[mf], br[nf], acc[mh * 4 + mf][nf], 0, 0, 0);
    };

    // prologue: stage tile 0 only; prove resident; pre-read tile0 mh0+breg
    stageA(0); stageB(0);
    asm volatile("s_waitcnt vmcnt(0)" ::: "memory");
    __builtin_amdgcn_s_barrier();
    __builtin_amdgcn_sched_barrier(0);
    lda(a0r, 0, 0); ldb(0);                          // 8 early reads, tile 0

    for (int t = 0; t < 36; ++t) {
        const int slot = t & 1;
        lda(a1r, slot, 1);                           // 4 reads (mh1); 12 outstanding
        if (t + 1 < 36) { stageA(t + 1); stageB(t + 1); }
        asm volatile("s_waitcnt lgkmcnt(4)" ::: "memory");   // a0r+br landed
        __builtin_amdgcn_sched_barrier(0);
        __builtin_amdgcn_s_setprio(1);
        mf16(a0r, 0);
        __builtin_amdgcn_s_setprio(0);
        asm volatile("s_waitcnt lgkmcnt(0)" ::: "memory");   // a1r landed
        __builtin_amdgcn_sched_barrier(0);
        __builtin_amdgcn_s_setprio(1);
        mf16(a1r, 1);
        __builtin_amdgcn_s_setprio(0);
        if (t + 1 < 36) { asm volatile("s_waitcnt vmcnt(0)" ::: "memory"); }
        __builtin_amdgcn_s_barrier();                // tile t+1 now globally resident
        __builtin_amdgcn_sched_barrier(0);
        if (t + 1 < 36) { lda(a0r, (t + 1) & 1, 0); ldb((t + 1) & 1); }  // 8 early reads
    }

    // epilogue: ragged max; D[row = 4q + r][col = i16]; leaf = acc + cl[col]
    int segc[4]; float clv[4];
    #pragma unroll
    for (int nf = 0; nf < 4; ++nf) {
        const int col = blockN + wn * 64 + nf * 16 + i16;
        segc[nf] = seg[col];
        clv[nf]  = cl[col];
    }
    #pragma unroll
    for (int mf = 0; mf < 8; ++mf)
        #pragma unroll
        for (int nf = 0; nf < 4; ++nf)
            #pragma unroll
            for (int r = 0; r < 4; ++r) {
                const int rl = wm * 128 + mf * 16 + 4 * q + r;
                atomicMax(&pmax[rl * 16 + segc[nf]], f2ord(acc[mf][nf][r] + clv[nf]));
            }
    __syncthreads();
    #pragma unroll
    for (int j = 0; j < 8; ++j) {
        int idx = tid + j * 512;                       // 0..4095
        atomicMax(&pooled[((blockM + (idx >> 4)) << 4) + (idx & 15)], pmax[idx]);
    }
}

// ---------------- finalize: softmax over pooled ----------------
__global__ __launch_bounds__(256) void finalize(const u32* __restrict__ pooled,
                                                float* __restrict__ out) {
    const int tid = threadIdx.x;
    const long row = (long)blockIdx.x * 16 + (tid >> 4);
    const int t = tid & 15;
    float logit = ord2f(pooled[(row << 4) + t]);
    float rm = logit;
    #pragma unroll
    for (int d = 8; d >= 1; d >>= 1) rm = fmaxf(rm, __shfl_xor(rm, d, 16));
    float e = __expf(logit - rm);
    float s = e;
    #pragma unroll
    for (int d = 8; d >= 1; d >>= 1) s += __shfl_xor(s, d, 16);
    out[(row << 4) + t] = e / s;
}

// ---------------- launch ----------------
extern "C" void kernel_launch(void* const* d_in, const int* in_sizes, int n_in,
                              void* d_out, int out_size, void* d_ws, size_t ws_size,
                              hipStream_t stream) {
    const float* x  = (const float*)d_in[0];
    const float* Wd = (const float*)d_in[1];
    const float* bd = (const float*)d_in[2];
    const float* Wa = (const float*)d_in[3];
    const float* ba = (const float*)d_in[4];
    const float* Wl = (const float*)d_in[5];
    const int*  seg = (const int*)d_in[6];
    float* out = (float*)d_out;

    char* ws = (char*)d_ws;
    u16*   xb   = (u16*)(ws);                      //   8,388,608 B  x bf16 [32768,128]
    u16*   w1b  = (u16*)(ws + 8388608);            //     262,144 B  W1 bf16 [1024,128]
    float* bb   = (float*)(ws + 8650752);          //       4,096 B  bias [1024]
    u16*   w1t  = (u16*)(ws + 8654848);            //     262,144 B  W1^T bf16 [128,1024]
    u16*   wsb  = (u16*)(ws + 8916992);            //   2,097,152 B  Ws bf16 [1024,1024]
    u16*   dlb  = (u16*)(ws + 11014144);           //   2,097,152 B  Dl bf16 [1024,1024]
    u16*   wcb  = (u16*)(ws + 13111296);           //     262,144 B  Wc bf16 [1024,128]
    float* clp  = (float*)(ws + 13373440);         //       4,096 B  cl fp32 [1024]
    u16*   habs = (u16*)(ws + 13377536);           //  67,108,864 B  |h| bf16 [32768,1024]
    u32*   pooled = (u32*)(ws + 80486400);         //   2,097,152 B  pooled u32 [32768][16]
    // total ws use: ~82.6 MiB

    setup_all<<<2632, 256, 0, stream>>>(x, Wd, bd, Wa, ba, Wl,
                                        xb, w1b, bb, w1t, wsb, dlb, clp, pooled);
    gemm_hwc <<<dim3(8, 257), 256, 0, stream>>>(xb, w1b, bb, dlb, w1t, habs, wcb);
    gemm_leaf<<<512, 512, 0, stream>>>(habs, xb, wsb, wcb, clp, seg, pooled);
    finalize <<<2048, 256, 0, stream>>>(pooled, out);
}

// Round 10
// 194.816 us; speedup vs baseline: 4.0663x; 4.0663x over previous
//
#include <hip/hip_runtime.h>
#include <hip/hip_bf16.h>
#include <cstdint>
#include <cmath>

#define AS1 __attribute__((address_space(1)))
#define AS3 __attribute__((address_space(3)))

typedef unsigned short u16;
typedef uint32_t u32;
typedef __attribute__((ext_vector_type(8))) __bf16 bf16x8;
typedef __attribute__((ext_vector_type(8))) unsigned short u16x8;
typedef __attribute__((ext_vector_type(4))) float f32x4;

// R24: leaf = R22 4-slot structure (88.1us, launch_bounds(512,2) — R23's (512,4)
// capped VGPR at 64 and spilled 3.5GB/dispatch; LESSON: this tile needs >128
// regs/wave, TLP unreachable) + fine-grained lgkm gate ladder (MFMA starts
// after 5 reads instead of 8). gemm_hwc keeps R23's correctness-proven 2-slot
// rolling h-role. setup/finalize unchanged.

// fp32 -> bf16 round-to-nearest-even
__device__ __forceinline__ u16 f2bf(float f) {
    uint32_t u = __builtin_bit_cast(uint32_t, f);
    return (u16)((u + 0x7fffu + ((u >> 16) & 1u)) >> 16);
}

// order-preserving float -> u32 map (for integer atomicMax); 0 is below all reals
__device__ __forceinline__ u32 f2ord(float f) {
    u32 u = __builtin_bit_cast(u32, f);
    return u ^ (u32)(((int32_t)u >> 31) | 0x80000000);
}
__device__ __forceinline__ float ord2f(u32 v) {
    u32 u = (v & 0x80000000u) ? (v ^ 0x80000000u) : ~v;
    return __builtin_bit_cast(float, u);
}

// SWIZZLE (R16-proven, both-sides involution, rule #21): LDS panels [rows][32 u16]
// (64 B row stride). LDS[row][chunk c] holds GLOBAL chunk c ^ ((row>>1)&3), staged
// via pre-swizzled global source (LDS dest stays linear for global_load_lds);
// read chunk = q ^ ((i16>>1)&3) -> registers hold the STANDARD fragment.
//   stage key: (tid>>3)&3   read key: (i16>>1)&3

// ---------------- fused setup (= R19) ----------------
// ALGEBRA: relu(h)=(h+|h|)/2, relu(-h)=(|h|-h)/2  =>
//   leaf = |h| @ Ws^T + x @ Wc^T + cl
__global__ void setup_all(const float* __restrict__ x,
                          const float* __restrict__ Wd, const float* __restrict__ bd,
                          const float* __restrict__ Wa, const float* __restrict__ ba,
                          const float* __restrict__ Wl,
                          u16* __restrict__ xb, u16* __restrict__ w1b,
                          float* __restrict__ bb, u16* __restrict__ w1t,
                          u16* __restrict__ wsb, u16* __restrict__ dlb,
                          float* __restrict__ cl, u32* __restrict__ pooled) {
    __shared__ float cred[256];
    const int b = blockIdx.x;
    const int tid = threadIdx.x;
    if (b < 2048) {
        long idx = (long)(b * 256 + tid) * 8;
        float4 a = *(const float4*)(x + idx);
        float4 c = *(const float4*)(x + idx + 4);
        u16x8 o;
        o[0]=f2bf(a.x); o[1]=f2bf(a.y); o[2]=f2bf(a.z); o[3]=f2bf(a.w);
        o[4]=f2bf(c.x); o[5]=f2bf(c.y); o[6]=f2bf(c.z); o[7]=f2bf(c.w);
        *(u16x8*)(xb + idx) = o;
    } else if (b < 2112) {
        int t = (b - 2048) * 256 + tid;   // 16384 threads
        int row = t >> 4, g = (t & 15) * 8;
        const float* src = nullptr;
        if (row < 511)       src = Wd + row * 128 + g;
        else if (row < 1023) src = Wa + (row - 511) * 128 + g;
        u16x8 o = 0;
        if (src) {
            #pragma unroll
            for (int j = 0; j < 8; ++j) o[j] = f2bf(src[j]);
        }
        *(u16x8*)(w1b + row * 128 + g) = o;
        #pragma unroll
        for (int j = 0; j < 8; ++j) w1t[(g + j) * 1024 + row] = o[j];
        if ((t & 15) == 0)
            bb[row] = row < 511 ? bd[row] : (row < 1023 ? ba[row - 511] : 0.f);
    } else if (b < 2624) {
        const int l0 = (b - 2112) * 2;
        const int lo = tid >> 7, g = (tid & 127) * 8;
        const float* src = Wl + (long)(l0 + lo) * 2046;
        u16x8 os, od;
        float part = 0.f;
        #pragma unroll
        for (int j = 0; j < 8; ++j) {
            int c = g + j;
            float pa = 0.f, pb = 0.f;
            if (c < 1023) { pa = src[c]; pb = src[1023 + c]; }
            os[j] = f2bf(0.5f * (pa + pb));
            float v = pa - pb;
            od[j] = f2bf(v);
            float b1 = c < 511 ? bd[c] : (c < 1023 ? ba[c - 511] : 0.f);
            part += v * b1;
        }
        *(u16x8*)(wsb + (long)(l0 + lo) * 1024 + g) = os;
        *(u16x8*)(dlb + (long)(l0 + lo) * 1024 + g) = od;
        cred[tid] = part;
        __syncthreads();
        if (tid < 2) {
            float s = 0.f;
            #pragma unroll
            for (int k = 0; k < 128; ++k) s += cred[tid * 128 + k];
            cl[l0 + tid] = 0.5f * s;
        }
    } else {
        // zero pooled[32768][16] u32 (2 MB) — every iteration
        uint4* p4 = (uint4*)pooled;            // 131072 uint4
        const int base = (b - 2624) * 16384;   // 8 blocks x 16384 uint4
        #pragma unroll
        for (int j = 0; j < 64; ++j)
            p4[base + tid + j * 256] = uint4{0u, 0u, 0u, 0u};
    }
}

// ---------------- gemm_hwc: R19 grid/layout; h-role = R23 2-slot rolling ----------
__global__ __launch_bounds__(256) void gemm_hwc(
        const u16* __restrict__ xb, const u16* __restrict__ w1b,
        const float* __restrict__ bb,
        const u16* __restrict__ dlb, const u16* __restrict__ w1t,
        u16* __restrict__ habs, u16* __restrict__ wcb) {
    __shared__ union SharedU {
        struct { u16 As[2][4096]; u16 Bs[2][4096]; } s;  // 32 KB, 2 K32-slots
        u16 obuf[128 * 132];                             // 33.8 KB epilogue overlay
    } sh;
    const int tid  = threadIdx.x;
    const int lane = tid & 63, wave = tid >> 6;
    const int wy = wave >> 1, wx = wave & 1;
    const int i16 = lane & 15, q = lane >> 4;
    const int cA = wave * 2, srow = lane >> 2;
    const int scol = (((lane & 3) ^ ((lane >> 3) & 3))) * 8;  // source-swizzled chunk
    const int qa   = (q ^ ((i16 >> 1) & 3)) * 8;              // swizzled read chunk

    f32x4 acc[4][4];
    #pragma unroll
    for (int m = 0; m < 4; ++m)
        #pragma unroll
        for (int n = 0; n < 4; ++n) acc[m][n] = f32x4{0.f,0.f,0.f,0.f};

    if (blockIdx.y == 0) {
        // ---- wc role (= R19 verbatim): Wc = 0.5*dlb@w1t^T, K=1024, BK=32 ----
        const long blockM = (long)blockIdx.x * 128;
        const int koff = (blockIdx.x * 4) & 31;
        const u16* a0 = dlb + (blockM + cA * 16 + srow) * 1024 + scol;
        const u16* a1 = dlb + (blockM + (cA + 1) * 16 + srow) * 1024 + scol;
        const u16* b0 = w1t + (long)(cA * 16 + srow) * 1024 + scol;
        const u16* b1 = w1t + (long)((cA + 1) * 16 + srow) * 1024 + scol;
        for (int it = 0; it < 32; ++it) {
            const int k0 = ((it + koff) & 31) << 5;
            __builtin_amdgcn_global_load_lds((const AS1 void*)(a0 + k0), (AS3 void*)&sh.s.As[0][cA * 512],       16, 0, 0);
            __builtin_amdgcn_global_load_lds((const AS1 void*)(a1 + k0), (AS3 void*)&sh.s.As[0][(cA + 1) * 512], 16, 0, 0);
            __builtin_amdgcn_global_load_lds((const AS1 void*)(b0 + k0), (AS3 void*)&sh.s.Bs[0][cA * 512],       16, 0, 0);
            __builtin_amdgcn_global_load_lds((const AS1 void*)(b1 + k0), (AS3 void*)&sh.s.Bs[0][(cA + 1) * 512], 16, 0, 0);
            __syncthreads();
            bf16x8 af[4], bfv[4];
            #pragma unroll
            for (int s = 0; s < 4; ++s) {
                af[s]  = *(const bf16x8*)&sh.s.As[0][(wy * 64 + s * 16 + i16) * 32 + qa];
                bfv[s] = *(const bf16x8*)&sh.s.Bs[0][(wx * 64 + s * 16 + i16) * 32 + qa];
            }
            #pragma unroll
            for (int sm = 0; sm < 4; ++sm)
                #pragma unroll
                for (int sn = 0; sn < 4; ++sn)
                    acc[sm][sn] = __builtin_amdgcn_mfma_f32_16x16x32_bf16(af[sm], bfv[sn], acc[sm][sn], 0, 0, 0);
            __syncthreads();
        }
        #pragma unroll
        for (int sm = 0; sm < 4; ++sm)
            #pragma unroll
            for (int sn = 0; sn < 4; ++sn) {
                const int col = wx * 64 + sn * 16 + i16;     // 0..127
                #pragma unroll
                for (int r = 0; r < 4; ++r) {
                    const long row = blockM + wy * 64 + sm * 16 + 4 * q + r;
                    wcb[row * 128 + col] = f2bf(0.5f * acc[sm][sn][r]);
                }
            }
        return;
    }

    // ---- h role: habs = |xb @ w1b^T + bb|, K=128 = 4 K32-tiles, 2-slot rolling ----
    const int xcd = blockIdx.x, yy = blockIdx.y - 1;   // yy in 0..255
    const long blockM = (long)(xcd * 32 + (yy >> 3)) * 128;
    const int  blockN = (yy & 7) * 128;

    const u16* a0 = xb + (blockM + cA * 16 + srow) * 128 + scol;
    const u16* a1 = xb + (blockM + (cA + 1) * 16 + srow) * 128 + scol;
    const u16* b0 = w1b + ((long)blockN + cA * 16 + srow) * 128 + scol;
    const u16* b1 = w1b + ((long)blockN + (cA + 1) * 16 + srow) * 128 + scol;
    auto hstage = [&](int tt) {            // one K32 tile = 4 ops/thread
        const int sl = tt & 1, kp = tt * 32;
        __builtin_amdgcn_global_load_lds((const AS1 void*)(a0 + kp), (AS3 void*)&sh.s.As[sl][cA * 512],       16, 0, 0);
        __builtin_amdgcn_global_load_lds((const AS1 void*)(a1 + kp), (AS3 void*)&sh.s.As[sl][(cA + 1) * 512], 16, 0, 0);
        __builtin_amdgcn_global_load_lds((const AS1 void*)(b0 + kp), (AS3 void*)&sh.s.Bs[sl][cA * 512],       16, 0, 0);
        __builtin_amdgcn_global_load_lds((const AS1 void*)(b1 + kp), (AS3 void*)&sh.s.Bs[sl][(cA + 1) * 512], 16, 0, 0);
    };
    hstage(0);
    asm volatile("s_waitcnt vmcnt(0)" ::: "memory");
    __builtin_amdgcn_s_barrier();
    #pragma unroll
    for (int kt = 0; kt < 4; ++kt) {
        const int sl = kt & 1;
        __builtin_amdgcn_sched_barrier(0);
        bf16x8 af[4], bfv[4];
        #pragma unroll
        for (int s = 0; s < 4; ++s) {
            af[s]  = *(const bf16x8*)&sh.s.As[sl][(wy * 64 + s * 16 + i16) * 32 + qa];
            bfv[s] = *(const bf16x8*)&sh.s.Bs[sl][(wx * 64 + s * 16 + i16) * 32 + qa];
        }
        if (kt + 1 < 4) hstage(kt + 1);    // other slot; WAR: last read at kt-1, drained
        asm volatile("s_waitcnt lgkmcnt(0)" ::: "memory");
        __builtin_amdgcn_sched_barrier(0);
        __builtin_amdgcn_s_setprio(1);
        #pragma unroll
        for (int sm = 0; sm < 4; ++sm)
            #pragma unroll
            for (int sn = 0; sn < 4; ++sn)
                acc[sm][sn] = __builtin_amdgcn_mfma_f32_16x16x32_bf16(af[sm], bfv[sn], acc[sm][sn], 0, 0, 0);
        __builtin_amdgcn_s_setprio(0);
        if (kt + 1 < 4) { asm volatile("s_waitcnt vmcnt(0)" ::: "memory"); }
        __builtin_amdgcn_s_barrier();      // tile kt+1 resident; also final pre-obuf sync
    }

    float bv[4];
    #pragma unroll
    for (int sn = 0; sn < 4; ++sn) bv[sn] = bb[blockN + wx * 64 + sn * 16 + i16];
    #pragma unroll
    for (int sm = 0; sm < 4; ++sm)
        #pragma unroll
        for (int sn = 0; sn < 4; ++sn)
            #pragma unroll
            for (int r = 0; r < 4; ++r)
                sh.obuf[(wy * 64 + sm * 16 + 4 * q + r) * 132 + wx * 64 + sn * 16 + i16] =
                    f2bf(fabsf(acc[sm][sn][r] + bv[sn]));
    __syncthreads();
    const int cg = (tid & 15) * 8;
    #pragma unroll
    for (int it = 0; it < 8; ++it) {
        const int row = it * 16 + (tid >> 4);
        *(u16x8*)&habs[(blockM + row) * 1024 + blockN + cg] =
            *(const u16x8*)&sh.obuf[row * 132 + cg];
    }
}

// ---------------- GEMM2 (R24): R22 4-slot + fine-grained lgkm gate ladder --------
// leaf = habs@Ws^T + xb@Wc^T + cl, fused ragged-max -> global atomicMax(pooled).
// K-tiles t=0..31: habs/wsb (stride 1024); t=32..35: xb/wcb (stride 128).
// Read issue order (unchanged from R22): early a0r[0..3],br[0..3] after barrier;
// loop-top a1r[0..3]. NEW: instead of lgkm(4)->16 MFMA->lgkm(0)->16 MFMA, an
// 8-step ladder lets MFMA start after 5 reads: lgkm(7)->col0, (6)->col1,
// (5)->col2, (4)->col3, (3)->row0(mh1), (2)->row1, (1)->row2, (0)->row3.
// vmcnt/slot/WAR ledger byte-identical to R22 (passed, 88.1us).
__global__ __launch_bounds__(512, 2) void gemm_leaf(const u16* __restrict__ habs,
        const u16* __restrict__ xb, const u16* __restrict__ wsb,
        const u16* __restrict__ wcb, const float* __restrict__ cl,
        const int* __restrict__ seg, u32* __restrict__ pooled) {
    __shared__ __align__(16) u16 As[4][256 * 32];   // 64 KB, 4 K32-slots
    __shared__ __align__(16) u16 Bs[4][256 * 32];   // 64 KB
    __shared__ u32 pmax[256 * 16];                  // 16 KB
    const int tid  = threadIdx.x;
    const int lane = tid & 63, w = tid >> 6;
    const int wm = w >> 2, wn = w & 3;              // 2x4 wave grid, wave tile 128x64
    const int i16 = lane & 15, q = lane >> 4;

    // XCD-aware swizzle over 512 blocks (512%8==0 -> bijective)
    const int bid  = blockIdx.x;
    const int wgid = (bid & 7) * 64 + (bid >> 3);
    const int mT = wgid >> 2, nT = wgid & 3;
    const long blockM = (long)mT * 256;
    const int  blockN = nT * 256;

    #pragma unroll
    for (int j = 0; j < 8; ++j) pmax[tid + j * 512] = 0u;   // below all reals

    const int r0 = tid >> 2;
    const int scol = (((tid & 3) ^ ((tid >> 3) & 3))) * 8;
    const u16* gA1 = habs + (blockM + r0) * 1024 + scol;
    const u16* gB1 = wsb  + (long)(blockN + r0) * 1024 + scol;
    const u16* gA2 = xb   + (blockM + r0) * 128 + scol;
    const u16* gB2 = wcb  + (long)(blockN + r0) * 128 + scol;
    const int ldsb = w * 512;                       // wave-uniform dest base (u16)

    auto stageA = [&](int tt) {
        u16* dst = &As[tt & 3][ldsb];
        const u16* g; int jstr;
        if (tt < 32) { g = gA1 + tt * 32;        jstr = 128 * 1024; }
        else         { g = gA2 + (tt - 32) * 32; jstr = 128 * 128; }
        __builtin_amdgcn_global_load_lds((const AS1 void*)g,          (AS3 void*)dst,          16, 0, 0);
        __builtin_amdgcn_global_load_lds((const AS1 void*)(g + jstr), (AS3 void*)(dst + 4096), 16, 0, 0);
    };
    auto stageB = [&](int tt) {
        u16* dst = &Bs[tt & 3][ldsb];
        const u16* g; int jstr;
        if (tt < 32) { g = gB1 + tt * 32;        jstr = 128 * 1024; }
        else         { g = gB2 + (tt - 32) * 32; jstr = 128 * 128; }
        __builtin_amdgcn_global_load_lds((const AS1 void*)g,          (AS3 void*)dst,          16, 0, 0);
        __builtin_amdgcn_global_load_lds((const AS1 void*)(g + jstr), (AS3 void*)(dst + 4096), 16, 0, 0);
    };

    f32x4 acc[8][4];
    #pragma unroll
    for (int m = 0; m < 8; ++m)
        #pragma unroll
        for (int n = 0; n < 4; ++n) acc[m][n] = f32x4{0.f,0.f,0.f,0.f};
    bf16x8 a0r[4], a1r[4], br[4];

    const int rdc = (q ^ ((i16 >> 1) & 3)) * 8;     // swizzled read chunk (u16 off)
    auto lda = [&](bf16x8* ar, int slot, int mh) {
        #pragma unroll
        for (int mf = 0; mf < 4; ++mf)
            ar[mf] = *(const bf16x8*)&As[slot][(wm * 128 + mh * 64 + mf * 16 + i16) * 32 + rdc];
    };
    auto ldb = [&](int slot) {
        #pragma unroll
        for (int nf = 0; nf < 4; ++nf)
            br[nf] = *(const bf16x8*)&Bs[slot][(wn * 64 + nf * 16 + i16) * 32 + rdc];
    };
    // fine-grained MFMA groups
    auto mfCol = [&](int nf) {            // mh0 column nf: needs a0r[0..3] + br[nf]
        #pragma unroll
        for (int mf = 0; mf < 4; ++mf)
            acc[mf][nf] = __builtin_amdgcn_mfma_f32_16x16x32_bf16(
                a0r[mf], br[nf], acc[mf][nf], 0, 0, 0);
    };
    auto mfRow = [&](int mf) {            // mh1 row mf: needs a1r[mf] + br[0..3]
        #pragma unroll
        for (int nf = 0; nf < 4; ++nf)
            acc[4 + mf][nf] = __builtin_amdgcn_mfma_f32_16x16x32_bf16(
                a1r[mf], br[nf], acc[4 + mf][nf], 0, 0, 0);
    };

    // prologue: tiles 0,1 staged; tile0 proven resident; pre-read tile0 a0r,br
    stageA(0); stageB(0); stageA(1); stageB(1);
    asm volatile("s_waitcnt vmcnt(4)" ::: "memory");
    __builtin_amdgcn_s_barrier();
    __builtin_amdgcn_sched_barrier(0);
    lda(a0r, 0, 0); ldb(0);                          // 8 early reads, tile 0

    for (int t = 0; t < 36; ++t) {
        const int slot = t & 3;
        lda(a1r, slot, 1);                           // 4 reads (mh1); 12 outstanding
        if (t + 2 < 36) { stageA(t + 2); stageB(t + 2); }
        __builtin_amdgcn_s_setprio(1);
        asm volatile("s_waitcnt lgkmcnt(7)" ::: "memory");   // a0r[0..3]+br[0]
        __builtin_amdgcn_sched_barrier(0);
        mfCol(0);
        asm volatile("s_waitcnt lgkmcnt(6)" ::: "memory");   // +br[1]
        __builtin_amdgcn_sched_barrier(0);
        mfCol(1);
        asm volatile("s_waitcnt lgkmcnt(5)" ::: "memory");   // +br[2]
        __builtin_amdgcn_sched_barrier(0);
        mfCol(2);
        asm volatile("s_waitcnt lgkmcnt(4)" ::: "memory");   // +br[3]
        __builtin_amdgcn_sched_barrier(0);
        mfCol(3);
        asm volatile("s_waitcnt lgkmcnt(3)" ::: "memory");   // +a1r[0]
        __builtin_amdgcn_sched_barrier(0);
        mfRow(0);
        asm volatile("s_waitcnt lgkmcnt(2)" ::: "memory");   // +a1r[1]
        __builtin_amdgcn_sched_barrier(0);
        mfRow(1);
        asm volatile("s_waitcnt lgkmcnt(1)" ::: "memory");   // +a1r[2]
        __builtin_amdgcn_sched_barrier(0);
        mfRow(2);
        asm volatile("s_waitcnt lgkmcnt(0)" ::: "memory");   // +a1r[3]
        __builtin_amdgcn_sched_barrier(0);
        mfRow(3);
        __builtin_amdgcn_s_setprio(0);
        if (t < 34)       { asm volatile("s_waitcnt vmcnt(4)" ::: "memory"); }
        else if (t == 34) { asm volatile("s_waitcnt vmcnt(0)" ::: "memory"); }
        __builtin_amdgcn_s_barrier();                // tile t+1 now globally resident
        __builtin_amdgcn_sched_barrier(0);
        if (t + 1 < 36) { lda(a0r, (t + 1) & 3, 0); ldb((t + 1) & 3); }  // 8 early reads
    }

    // epilogue: ragged max; D[row = 4q + r][col = i16]; leaf = acc + cl[col]
    int segc[4]; float clv[4];
    #pragma unroll
    for (int nf = 0; nf < 4; ++nf) {
        const int col = blockN + wn * 64 + nf * 16 + i16;
        segc[nf] = seg[col];
        clv[nf]  = cl[col];
    }
    #pragma unroll
    for (int mf = 0; mf < 8; ++mf)
        #pragma unroll
        for (int nf = 0; nf < 4; ++nf)
            #pragma unroll
            for (int r = 0; r < 4; ++r) {
                const int rl = wm * 128 + mf * 16 + 4 * q + r;
                atomicMax(&pmax[rl * 16 + segc[nf]], f2ord(acc[mf][nf][r] + clv[nf]));
            }
    __syncthreads();
    #pragma unroll
    for (int j = 0; j < 8; ++j) {
        int idx = tid + j * 512;                       // 0..4095
        atomicMax(&pooled[((blockM + (idx >> 4)) << 4) + (idx & 15)], pmax[idx]);
    }
}

// ---------------- finalize: softmax over pooled ----------------
__global__ __launch_bounds__(256) void finalize(const u32* __restrict__ pooled,
                                                float* __restrict__ out) {
    const int tid = threadIdx.x;
    const long row = (long)blockIdx.x * 16 + (tid >> 4);
    const int t = tid & 15;
    float logit = ord2f(pooled[(row << 4) + t]);
    float rm = logit;
    #pragma unroll
    for (int d = 8; d >= 1; d >>= 1) rm = fmaxf(rm, __shfl_xor(rm, d, 16));
    float e = __expf(logit - rm);
    float s = e;
    #pragma unroll
    for (int d = 8; d >= 1; d >>= 1) s += __shfl_xor(s, d, 16);
    out[(row << 4) + t] = e / s;
}

// ---------------- launch ----------------
extern "C" void kernel_launch(void* const* d_in, const int* in_sizes, int n_in,
                              void* d_out, int out_size, void* d_ws, size_t ws_size,
                              hipStream_t stream) {
    const float* x  = (const float*)d_in[0];
    const float* Wd = (const float*)d_in[1];
    const float* bd = (const float*)d_in[2];
    const float* Wa = (const float*)d_in[3];
    const float* ba = (const float*)d_in[4];
    const float* Wl = (const float*)d_in[5];
    const int*  seg = (const int*)d_in[6];
    float* out = (float*)d_out;

    char* ws = (char*)d_ws;
    u16*   xb   = (u16*)(ws);                      //   8,388,608 B  x bf16 [32768,128]
    u16*   w1b  = (u16*)(ws + 8388608);            //     262,144 B  W1 bf16 [1024,128]
    float* bb   = (float*)(ws + 8650752);          //       4,096 B  bias [1024]
    u16*   w1t  = (u16*)(ws + 8654848);            //     262,144 B  W1^T bf16 [128,1024]
    u16*   wsb  = (u16*)(ws + 8916992);            //   2,097,152 B  Ws bf16 [1024,1024]
    u16*   dlb  = (u16*)(ws + 11014144);           //   2,097,152 B  Dl bf16 [1024,1024]
    u16*   wcb  = (u16*)(ws + 13111296);           //     262,144 B  Wc bf16 [1024,128]
    float* clp  = (float*)(ws + 13373440);         //       4,096 B  cl fp32 [1024]
    u16*   habs = (u16*)(ws + 13377536);           //  67,108,864 B  |h| bf16 [32768,1024]
    u32*   pooled = (u32*)(ws + 80486400);         //   2,097,152 B  pooled u32 [32768][16]
    // total ws use: ~82.6 MiB

    setup_all<<<2632, 256, 0, stream>>>(x, Wd, bd, Wa, ba, Wl,
                                        xb, w1b, bb, w1t, wsb, dlb, clp, pooled);
    gemm_hwc <<<dim3(8, 257), 256, 0, stream>>>(xb, w1b, bb, dlb, w1t, habs, wcb);
    gemm_leaf<<<512, 512, 0, stream>>>(habs, xb, wsb, wcb, clp, seg, pooled);
    finalize <<<2048, 256, 0, stream>>>(pooled, out);
}